// Round 6
// baseline (675.574 us; speedup 1.0000x reference)
//
#include <hip/hip_runtime.h>
#include <hip/hip_bf16.h>
#include <stdint.h>

#define N_ATOMS 65536
#define N_BONDS 131072
#define N_MOLS  512
#define D_IN    16
#define DD      128
#define REPEAT  3
#define PITCH   136   // LDS row pitch (bf16)

typedef __attribute__((ext_vector_type(8))) short s8b;
typedef __attribute__((ext_vector_type(4))) float f32x4;

__device__ __forceinline__ float us2f(unsigned short s) {
    unsigned int u = ((unsigned int)s) << 16;
    float f; __builtin_memcpy(&f, &u, 4); return f;
}
__device__ __forceinline__ unsigned short f2us(float f) {
    __hip_bfloat16 h = __float2bfloat16(f);
    unsigned short s; __builtin_memcpy(&s, &h, 2); return s;
}
__device__ __forceinline__ void acc8(float* a, uint4 v) {
    unsigned short w[8]; __builtin_memcpy(w, &v, 16);
#pragma unroll
    for (int j = 0; j < 8; j++) a[j] += us2f(w[j]);
}

// ---------------- one-time prep ----------------

// Pack W[K][128] fp32 -> bf16 fragment order: Wpk[((c*4+ks)*4+quad)*128 + n][8]
__global__ void k_pack_w(const float* __restrict__ W, unsigned short* __restrict__ Wpk, int K) {
    int idx = blockIdx.x * 256 + threadIdx.x;     // K*128
    if (idx >= K * 128) return;
    int k = idx >> 7, n = idx & 127;
    int c = k >> 7, ks = (k >> 5) & 3, quad = (k >> 3) & 3, j = k & 7;
    int pidx = (((c * 4 + ks) * 4 + quad) * 128 + n) * 8 + j;
    Wpk[pidx] = f2us(W[k * 128 + n]);
}

__global__ void k_deg(const int* __restrict__ bsrc, const int* __restrict__ bdst,
                      int* __restrict__ deg) {
    int e = blockIdx.x * 256 + threadIdx.x;
    atomicAdd(&deg[bsrc[e]], 1);
    atomicAdd(&deg[bdst[e]], 1);
}

__global__ void k_scan(const int* __restrict__ deg, int* __restrict__ rowptr,
                       int* __restrict__ cursor) {
    __shared__ int part[1024];
    int t = threadIdx.x;
    int base = t * 64;
    int s = 0;
    for (int i = 0; i < 64; i++) s += deg[base + i];
    part[t] = s;
    __syncthreads();
    if (t == 0) {
        int run = 0;
        for (int i = 0; i < 1024; i++) { int v = part[i]; part[i] = run; run += v; }
    }
    __syncthreads();
    int off = part[t];
    for (int i = 0; i < 64; i++) {
        rowptr[base + i] = off;
        cursor[base + i] = off;
        off += deg[base + i];
    }
    if (t == 1023) rowptr[N_ATOMS] = off;
}

__global__ void k_fill(const int* __restrict__ bsrc, const int* __restrict__ bdst,
                       int* __restrict__ cursor, int* __restrict__ adj) {
    int e = blockIdx.x * 256 + threadIdx.x;
    int p = atomicAdd(&cursor[bsrc[e]], 1); adj[p] = e;
    int q = atomicAdd(&cursor[bdst[e]], 1); adj[q] = e;
}

// mol_ptr[m] = lower_bound(ids, m); one block >= 513 threads
__global__ void k_molptr(const int* __restrict__ ids, int rows, int* __restrict__ mptr) {
    int m = threadIdx.x;
    if (m > N_MOLS) return;
    int lo = 0, hi = rows;
    while (lo < hi) {
        int mid = (lo + hi) >> 1;
        if (ids[mid] < m) lo = mid + 1; else hi = mid;
    }
    mptr[m] = lo;
}

// ---------------- init ----------------

__global__ void k_init_edges(const float* __restrict__ bo, const float* __restrict__ Wfe,
                             const float* __restrict__ bfe, unsigned short* __restrict__ he) {
    int idx = blockIdx.x * 256 + threadIdx.x;
    int e = idx >> 7, d = idx & 127;
    he[idx] = f2us(fmaxf(fmaf(bo[e], Wfe[d], bfe[d]), 0.f));
}

__global__ void k_init_nodes(const float* __restrict__ atoms, const float* __restrict__ Wfv,
                             const float* __restrict__ bfv, unsigned short* __restrict__ hv) {
    int idx = blockIdx.x * 256 + threadIdx.x;
    int n = idx >> 7, d = idx & 127;
    float acc = bfv[d];
#pragma unroll
    for (int k = 0; k < D_IN; k++)
        acc = fmaf(atoms[n*D_IN + k], Wfv[k*DD + d], acc);
    hv[idx] = f2us(fmaxf(acc, 0.f));
}

// split per-molecule sum: S contiguous sub-ranges per mol; one atomic per col per block.
__global__ __launch_bounds__(256) void k_molsum_s(const unsigned short* __restrict__ x,
                                                  const int* __restrict__ mptr,
                                                  float* __restrict__ out, int S) {
    __shared__ float red[16 * 128];
    int m = blockIdx.x / S, s = blockIdx.x - m * S;
    int b = mptr[m], e = mptr[m + 1];
    int len = (e - b + S - 1) / S;
    int r0 = b + s * len;
    int r1 = min(r0 + len, e);
    int rl = threadIdx.x >> 4, g = threadIdx.x & 15;
    float acc[8] = {0,0,0,0,0,0,0,0};
    for (int r = r0 + rl; r < r1; r += 16)
        acc8(acc, *reinterpret_cast<const uint4*>(x + (size_t)r * DD + g * 8));
#pragma unroll
    for (int j = 0; j < 8; j++) red[rl * 128 + g * 8 + j] = acc[j];
    __syncthreads();
    if (threadIdx.x < 128) {
        int col = threadIdx.x;
        float sum = 0.f;
#pragma unroll
        for (int i = 0; i < 16; i++) sum += red[i * 128 + col];
        if (sum != 0.f || true) atomicAdd(&out[(size_t)m * DD + col], sum);
    }
}

__global__ void k_mol_init(const float* __restrict__ ns, const float* __restrict__ Wfu,
                           const float* __restrict__ bfu, float* __restrict__ hu0) {
    int idx = blockIdx.x * 256 + threadIdx.x;
    int m = idx >> 7, d = idx & 127;
    float acc = bfu[d];
    for (int k = 0; k < DD; k++)
        acc = fmaf(ns[m*DD + k], Wfu[k*DD + d], acc);
    hu0[idx] = fmaxf(acc, 0.f);
}

// per-round tiny GEMMs: yue[m][d] = be[d] + sum_k hu[m][k]*We[(512+k)*128+d]
__global__ void k_yrow(const float* __restrict__ hu, const float* __restrict__ W,
                       const float* __restrict__ bias, float* __restrict__ y, int row0) {
    int idx = blockIdx.x * 256 + threadIdx.x;   // M*D
    int m = idx >> 7, d = idx & 127;
    float acc = bias[d];
    for (int k = 0; k < DD; k++)
        acc = fmaf(hu[m*DD + k], W[(row0 + k)*DD + d], acc);
    y[idx] = acc;
}

// ---------------- precompute packed GEMM partials (C-fragment order) ----------------
// yp[(blk*16 + nt*8 + mt)*256 + tid] = 4 bf16 partials (r=0..3) for that thread's C slots.
// Computes x_rows @ W(chunk wc) for 128-row block; x read from state buffer (== x0 at init).
__global__ __launch_bounds__(256) void k_pre(const unsigned short* __restrict__ x,
                                             const unsigned short* __restrict__ Wpk,
                                             uint2* __restrict__ yp, int wc) {
    __shared__ __align__(16) unsigned short xs[128 * PITCH];
    int tid = threadIdx.x;
    int r0 = blockIdx.x * 128;
    int wv = tid >> 6, lane = tid & 63, quad = lane >> 4, l15 = lane & 15;
    f32x4 acc[8][2];
#pragma unroll
    for (int mt = 0; mt < 8; mt++)
#pragma unroll
        for (int nt = 0; nt < 2; nt++)
            acc[mt][nt] = (f32x4){0.f, 0.f, 0.f, 0.f};
    for (int u = tid; u < 128 * 16; u += 256) {
        int i = u >> 4, g = (u & 15) * 8;
        *reinterpret_cast<uint4*>(&xs[i * PITCH + g]) =
            *reinterpret_cast<const uint4*>(x + (size_t)(r0 + i) * DD + g);
    }
    __syncthreads();
#pragma unroll
    for (int ks = 0; ks < 4; ks++) {
        const unsigned short* wb = Wpk + ((wc * 4 + ks) * 4 + quad) * 1024;
        s8b bfr[2];
#pragma unroll
        for (int nt = 0; nt < 2; nt++)
            bfr[nt] = *reinterpret_cast<const s8b*>(wb + (wv*32 + nt*16 + l15) * 8);
#pragma unroll
        for (int mt = 0; mt < 8; mt++) {
            s8b afr = *reinterpret_cast<const s8b*>(&xs[(mt*16 + l15) * PITCH + ks*32 + quad*8]);
#pragma unroll
            for (int nt = 0; nt < 2; nt++)
                acc[mt][nt] = __builtin_amdgcn_mfma_f32_16x16x32_bf16(afr, bfr[nt], acc[mt][nt], 0, 0, 0);
        }
    }
#pragma unroll
    for (int nt = 0; nt < 2; nt++)
#pragma unroll
        for (int mt = 0; mt < 8; mt++) {
            unsigned short o[4];
#pragma unroll
            for (int r = 0; r < 4; r++) o[r] = f2us(acc[mt][nt][r]);
            uint2 ov; __builtin_memcpy(&ov, o, 8);
            yp[((size_t)blockIdx.x * 16 + nt * 8 + mt) * 256 + tid] = ov;
        }
}

// ---------------- phi_e (MFMA, 3 chunks, reg-prefetch pipeline) ----------------
__global__ __launch_bounds__(256) void k_phi_e(
        unsigned short* __restrict__ he, const unsigned short* __restrict__ hv,
        const unsigned short* __restrict__ Wpk, const uint2* __restrict__ ye0p,
        const float* __restrict__ yue,
        const int* __restrict__ bsrc, const int* __restrict__ bdst) {
    __shared__ __align__(16) unsigned short xs[128 * PITCH];
    __shared__ int ssrc[128], sdst[128];
    int tid = threadIdx.x;
    int e0 = blockIdx.x * 128;
    if (tid < 128) {
        ssrc[tid] = bsrc[e0 + tid];
        sdst[tid] = bdst[e0 + tid];
    }
    int wv = tid >> 6, lane = tid & 63, quad = lane >> 4, l15 = lane & 15;
    f32x4 acc[8][2];
#pragma unroll
    for (int mt = 0; mt < 8; mt++)
#pragma unroll
        for (int nt = 0; nt < 2; nt++)
            acc[mt][nt] = (f32x4){0.f, 0.f, 0.f, 0.f};

    uint4 pf[8];
    auto prefetch = [&](int c) {
#pragma unroll
        for (int t = 0; t < 8; t++) {
            int u = tid + t * 256;
            int i = u >> 4, g = (u & 15) * 8;
            const unsigned short* src = (c == 0) ? he + (size_t)(e0 + i) * DD
                                      : (c == 1) ? hv + (size_t)ssrc[i] * DD
                                                 : hv + (size_t)sdst[i] * DD;
            pf[t] = *reinterpret_cast<const uint4*>(src + g);
        }
    };
    prefetch(0);                       // no ssrc dependency
    const int wc_e[3] = {0, 2, 3};
#pragma unroll
    for (int c = 0; c < 3; c++) {
        __syncthreads();               // xs free (and ssrc visible from here on)
#pragma unroll
        for (int t = 0; t < 8; t++) {
            int u = tid + t * 256;
            int i = u >> 4, g = (u & 15) * 8;
            *reinterpret_cast<uint4*>(&xs[i * PITCH + g]) = pf[t];
        }
        __syncthreads();               // xs ready
        if (c < 2) prefetch(c + 1);    // overlap next gather with MFMA
        int WC = wc_e[c];
#pragma unroll
        for (int ks = 0; ks < 4; ks++) {
            const unsigned short* wb = Wpk + ((WC * 4 + ks) * 4 + quad) * 1024;
            s8b bfr[2];
#pragma unroll
            for (int nt = 0; nt < 2; nt++)
                bfr[nt] = *reinterpret_cast<const s8b*>(wb + (wv*32 + nt*16 + l15) * 8);
#pragma unroll
            for (int mt = 0; mt < 8; mt++) {
                s8b afr = *reinterpret_cast<const s8b*>(&xs[(mt*16 + l15) * PITCH + ks*32 + quad*8]);
#pragma unroll
                for (int nt = 0; nt < 2; nt++)
                    acc[mt][nt] = __builtin_amdgcn_mfma_f32_16x16x32_bf16(afr, bfr[nt], acc[mt][nt], 0, 0, 0);
            }
        }
    }
    // epilogue: += ye0 partial (packed) + yue[mol] (bias folded), relu, store
    __shared__ int smol2[128];
    // note: bmol not needed here; yue indexed via bmol staged by caller? -> staged below
#pragma unroll
    for (int nt = 0; nt < 2; nt++) {
        int col = wv*32 + nt*16 + l15;
#pragma unroll
        for (int mt = 0; mt < 8; mt++) {
            uint2 pv = ye0p[((size_t)blockIdx.x * 16 + nt * 8 + mt) * 256 + tid];
            unsigned short y4[4]; __builtin_memcpy(y4, &pv, 8);
#pragma unroll
            for (int r = 0; r < 4; r++) {
                int rl = mt*16 + quad*4 + r;
                float v = acc[mt][nt][r] + us2f(y4[r]) + yue[(size_t)smol2[rl] * DD + col];
                he[(size_t)(e0 + rl) * DD + col] = f2us(fmaxf(v, 0.f));
            }
        }
    }
}

// variant with bmol staging done properly: wrapper kernel sets smol2.
// (to keep one kernel, we re-declare phi_e with bmol param below)

// ---------------- e_bar_i gather (CSR, vectorized, unroll-4) ----------------
__global__ __launch_bounds__(256) void k_ebar(const unsigned short* __restrict__ he,
                                              const int* __restrict__ rowptr,
                                              const int* __restrict__ adj,
                                              unsigned short* __restrict__ ebar_i) {
    int n = blockIdx.x * 16 + (threadIdx.x >> 4);
    int g = threadIdx.x & 15;
    int b = rowptr[n], e = rowptr[n + 1];
    float acc[8] = {0,0,0,0,0,0,0,0};
    int j = b;
    for (; j + 3 < e; j += 4) {
        uint4 v0 = *reinterpret_cast<const uint4*>(he + (size_t)adj[j]     * DD + g * 8);
        uint4 v1 = *reinterpret_cast<const uint4*>(he + (size_t)adj[j + 1] * DD + g * 8);
        uint4 v2 = *reinterpret_cast<const uint4*>(he + (size_t)adj[j + 2] * DD + g * 8);
        uint4 v3 = *reinterpret_cast<const uint4*>(he + (size_t)adj[j + 3] * DD + g * 8);
        acc8(acc, v0); acc8(acc, v1); acc8(acc, v2); acc8(acc, v3);
    }
    for (; j < e; j++)
        acc8(acc, *reinterpret_cast<const uint4*>(he + (size_t)adj[j] * DD + g * 8));
    unsigned short o[8];
#pragma unroll
    for (int k = 0; k < 8; k++) o[k] = f2us(acc[k]);
    uint4 ov; __builtin_memcpy(&ov, o, 16);
    *reinterpret_cast<uint4*>(ebar_i + (size_t)n * DD + g * 8) = ov;
}

// ---------------- phi_v (MFMA, 2 chunks, reg-prefetch pipeline) ----------------
__global__ __launch_bounds__(256) void k_phi_v(
        unsigned short* __restrict__ hv, const unsigned short* __restrict__ ebar_i,
        const unsigned short* __restrict__ Wpk, const uint2* __restrict__ yv0p,
        const float* __restrict__ yuv, const int* __restrict__ amol) {
    __shared__ __align__(16) unsigned short xs[128 * PITCH];
    __shared__ int smol[128];
    int tid = threadIdx.x;
    int n0 = blockIdx.x * 128;
    if (tid < 128) smol[tid] = amol[n0 + tid];
    int wv = tid >> 6, lane = tid & 63, quad = lane >> 4, l15 = lane & 15;
    f32x4 acc[8][2];
#pragma unroll
    for (int mt = 0; mt < 8; mt++)
#pragma unroll
        for (int nt = 0; nt < 2; nt++)
            acc[mt][nt] = (f32x4){0.f, 0.f, 0.f, 0.f};

    uint4 pf[8];
    auto prefetch = [&](int c) {
#pragma unroll
        for (int t = 0; t < 8; t++) {
            int u = tid + t * 256;
            int i = u >> 4, g = (u & 15) * 8;
            const unsigned short* src = (c == 0) ? hv + (size_t)(n0 + i) * DD
                                                 : ebar_i + (size_t)(n0 + i) * DD;
            pf[t] = *reinterpret_cast<const uint4*>(src + g);
        }
    };
    prefetch(0);
    const int wc_v[2] = {0, 2};
#pragma unroll
    for (int c = 0; c < 2; c++) {
        __syncthreads();
#pragma unroll
        for (int t = 0; t < 8; t++) {
            int u = tid + t * 256;
            int i = u >> 4, g = (u & 15) * 8;
            *reinterpret_cast<uint4*>(&xs[i * PITCH + g]) = pf[t];
        }
        __syncthreads();
        if (c < 1) prefetch(c + 1);
        int WC = wc_v[c];
#pragma unroll
        for (int ks = 0; ks < 4; ks++) {
            const unsigned short* wb = Wpk + ((WC * 4 + ks) * 4 + quad) * 1024;
            s8b bfr[2];
#pragma unroll
            for (int nt = 0; nt < 2; nt++)
                bfr[nt] = *reinterpret_cast<const s8b*>(wb + (wv*32 + nt*16 + l15) * 8);
#pragma unroll
            for (int mt = 0; mt < 8; mt++) {
                s8b afr = *reinterpret_cast<const s8b*>(&xs[(mt*16 + l15) * PITCH + ks*32 + quad*8]);
#pragma unroll
                for (int nt = 0; nt < 2; nt++)
                    acc[mt][nt] = __builtin_amdgcn_mfma_f32_16x16x32_bf16(afr, bfr[nt], acc[mt][nt], 0, 0, 0);
            }
        }
    }
#pragma unroll
    for (int nt = 0; nt < 2; nt++) {
        int col = wv*32 + nt*16 + l15;
#pragma unroll
        for (int mt = 0; mt < 8; mt++) {
            uint2 pv = yv0p[((size_t)blockIdx.x * 16 + nt * 8 + mt) * 256 + tid];
            unsigned short y4[4]; __builtin_memcpy(y4, &pv, 8);
#pragma unroll
            for (int r = 0; r < 4; r++) {
                int rl = mt*16 + quad*4 + r;
                float v = acc[mt][nt][r] + us2f(y4[r]) + yuv[(size_t)smol[rl] * DD + col];
                hv[(size_t)(n0 + rl) * DD + col] = f2us(fmaxf(v, 0.f));
            }
        }
    }
}

// ---------------- phi_u ----------------
__global__ void k_phi_u(const float* __restrict__ hu_in, const float* __restrict__ hu0,
                        const float* __restrict__ ebar, const float* __restrict__ vbar,
                        const float* __restrict__ Wu, const float* __restrict__ bu,
                        float* __restrict__ hu_out, float* __restrict__ dout) {
    int idx = blockIdx.x * 256 + threadIdx.x;
    int m = idx >> 7, d = idx & 127;
    float acc = bu[d];
    const float* segs[4] = { hu_in + m*DD, hu0 + m*DD, ebar + m*DD, vbar + m*DD };
    for (int s = 0; s < 4; s++) {
        const float* x = segs[s];
        const float* W = Wu + (s*DD)*DD + d;
        for (int k = 0; k < DD; k++)
            acc = fmaf(x[k], W[k*DD], acc);
    }
    float v = fmaxf(acc, 0.f);
    hu_out[idx] = v;
    dout[idx] = v;
}

// phi_e real entry (stages bmol into smol2 before the main body runs):
// implemented via a small wrapper: we pass bmol and copy it in the epilogue path.
// To keep a single kernel, redefine: the k_phi_e above references smol2 which we
// must fill; do it at kernel start.
__global__ __launch_bounds__(256) void k_phi_e2(
        unsigned short* __restrict__ he, const unsigned short* __restrict__ hv,
        const unsigned short* __restrict__ Wpk, const uint2* __restrict__ ye0p,
        const float* __restrict__ yue,
        const int* __restrict__ bsrc, const int* __restrict__ bdst,
        const int* __restrict__ bmol) {
    __shared__ __align__(16) unsigned short xs[128 * PITCH];
    __shared__ int ssrc[128], sdst[128], smol[128];
    int tid = threadIdx.x;
    int e0 = blockIdx.x * 128;
    if (tid < 128) {
        ssrc[tid] = bsrc[e0 + tid];
        sdst[tid] = bdst[e0 + tid];
        smol[tid] = bmol[e0 + tid];
    }
    int wv = tid >> 6, lane = tid & 63, quad = lane >> 4, l15 = lane & 15;
    f32x4 acc[8][2];
#pragma unroll
    for (int mt = 0; mt < 8; mt++)
#pragma unroll
        for (int nt = 0; nt < 2; nt++)
            acc[mt][nt] = (f32x4){0.f, 0.f, 0.f, 0.f};

    uint4 pf[8];
    auto prefetch = [&](int c) {
#pragma unroll
        for (int t = 0; t < 8; t++) {
            int u = tid + t * 256;
            int i = u >> 4, g = (u & 15) * 8;
            const unsigned short* src = (c == 0) ? he + (size_t)(e0 + i) * DD
                                      : (c == 1) ? hv + (size_t)ssrc[i] * DD
                                                 : hv + (size_t)sdst[i] * DD;
            pf[t] = *reinterpret_cast<const uint4*>(src + g);
        }
    };
    prefetch(0);
    const int wc_e[3] = {0, 2, 3};
#pragma unroll
    for (int c = 0; c < 3; c++) {
        __syncthreads();
#pragma unroll
        for (int t = 0; t < 8; t++) {
            int u = tid + t * 256;
            int i = u >> 4, g = (u & 15) * 8;
            *reinterpret_cast<uint4*>(&xs[i * PITCH + g]) = pf[t];
        }
        __syncthreads();
        if (c < 2) prefetch(c + 1);
        int WC = wc_e[c];
#pragma unroll
        for (int ks = 0; ks < 4; ks++) {
            const unsigned short* wb = Wpk + ((WC * 4 + ks) * 4 + quad) * 1024;
            s8b bfr[2];
#pragma unroll
            for (int nt = 0; nt < 2; nt++)
                bfr[nt] = *reinterpret_cast<const s8b*>(wb + (wv*32 + nt*16 + l15) * 8);
#pragma unroll
            for (int mt = 0; mt < 8; mt++) {
                s8b afr = *reinterpret_cast<const s8b*>(&xs[(mt*16 + l15) * PITCH + ks*32 + quad*8]);
#pragma unroll
                for (int nt = 0; nt < 2; nt++)
                    acc[mt][nt] = __builtin_amdgcn_mfma_f32_16x16x32_bf16(afr, bfr[nt], acc[mt][nt], 0, 0, 0);
            }
        }
    }
#pragma unroll
    for (int nt = 0; nt < 2; nt++) {
        int col = wv*32 + nt*16 + l15;
#pragma unroll
        for (int mt = 0; mt < 8; mt++) {
            uint2 pv = ye0p[((size_t)blockIdx.x * 16 + nt * 8 + mt) * 256 + tid];
            unsigned short y4[4]; __builtin_memcpy(y4, &pv, 8);
#pragma unroll
            for (int r = 0; r < 4; r++) {
                int rl = mt*16 + quad*4 + r;
                float v = acc[mt][nt][r] + us2f(y4[r]) + yue[(size_t)smol[rl] * DD + col];
                he[(size_t)(e0 + rl) * DD + col] = f2us(fmaxf(v, 0.f));
            }
        }
    }
}

// ---------------- launch ----------------

extern "C" void kernel_launch(void* const* d_in, const int* in_sizes, int n_in,
                              void* d_out, int out_size, void* d_ws, size_t ws_size,
                              hipStream_t stream) {
    const float* atoms = (const float*)d_in[0];
    const float* bo    = (const float*)d_in[1];
    const float* Wfe   = (const float*)d_in[2];
    const float* bfe   = (const float*)d_in[3];
    const float* Wfv   = (const float*)d_in[4];
    const float* bfv   = (const float*)d_in[5];
    const float* Wfu   = (const float*)d_in[6];
    const float* bfu   = (const float*)d_in[7];
    const float* We    = (const float*)d_in[8];
    const float* be    = (const float*)d_in[9];
    const float* Wv    = (const float*)d_in[10];
    const float* bv    = (const float*)d_in[11];
    const float* Wu    = (const float*)d_in[12];
    const float* bu    = (const float*)d_in[13];
    const int* bsrc    = (const int*)d_in[14];
    const int* bdst    = (const int*)d_in[15];
    const int* amol    = (const int*)d_in[16];
    const int* bmol    = (const int*)d_in[17];

    char* p = (char*)d_ws;
    auto alloc = [&](size_t bytes) {
        char* r = p;
        p += (bytes + 255) & ~(size_t)255;
        return r;
    };
    unsigned short* he     = (unsigned short*)alloc((size_t)N_BONDS * DD * 2);
    unsigned short* hv     = (unsigned short*)alloc((size_t)N_ATOMS * DD * 2);
    unsigned short* ebar_i = (unsigned short*)alloc((size_t)N_ATOMS * DD * 2);
    uint2* ye0p            = (uint2*)alloc((size_t)N_BONDS * DD / 4 * 8);   // E*128 bf16 pairs
    uint2* yv0p            = (uint2*)alloc((size_t)N_ATOMS * DD / 4 * 8);
    unsigned short* WeP    = (unsigned short*)alloc((size_t)640 * DD * 2);
    unsigned short* WvP    = (unsigned short*)alloc((size_t)512 * DD * 2);
    int* deg      = (int*)alloc((size_t)N_ATOMS * 4);
    int* rowptr   = (int*)alloc((size_t)(N_ATOMS + 1) * 4);
    int* cursor   = (int*)alloc((size_t)N_ATOMS * 4);
    int* adj      = (int*)alloc((size_t)2 * N_BONDS * 4);
    int* bmol_ptr = (int*)alloc((size_t)(N_MOLS + 1) * 4);
    int* amol_ptr = (int*)alloc((size_t)(N_MOLS + 1) * 4);
    float* node_sum = (float*)alloc((size_t)N_MOLS * DD * 4);
    float* hu0   = (float*)alloc((size_t)N_MOLS * DD * 4);
    float* huA   = (float*)alloc((size_t)N_MOLS * DD * 4);
    float* huB   = (float*)alloc((size_t)N_MOLS * DD * 4);
    float* ebar  = (float*)alloc((size_t)N_MOLS * DD * 4);
    float* vbar  = (float*)alloc((size_t)N_MOLS * DD * 4);
    float* yue   = (float*)alloc((size_t)N_MOLS * DD * 4);
    float* yuv   = (float*)alloc((size_t)N_MOLS * DD * 4);

    // ---- CSR + mol ranges ----
    hipMemsetAsync(deg, 0, (size_t)N_ATOMS * 4, stream);
    k_deg<<<N_BONDS/256, 256, 0, stream>>>(bsrc, bdst, deg);
    k_scan<<<1, 1024, 0, stream>>>(deg, rowptr, cursor);
    k_fill<<<N_BONDS/256, 256, 0, stream>>>(bsrc, bdst, cursor, adj);
    k_molptr<<<1, 1024, 0, stream>>>(bmol, N_BONDS, bmol_ptr);
    k_molptr<<<1, 1024, 0, stream>>>(amol, N_ATOMS, amol_ptr);

    // ---- weight packing ----
    k_pack_w<<<(640*DD)/256, 256, 0, stream>>>(We, WeP, 640);
    k_pack_w<<<(512*DD)/256, 256, 0, stream>>>(Wv, WvP, 512);

    // ---- init states + loop-invariant GEMM partials ----
    k_init_edges<<<(N_BONDS*DD)/256, 256, 0, stream>>>(bo, Wfe, bfe, he);
    k_init_nodes<<<(N_ATOMS*DD)/256, 256, 0, stream>>>(atoms, Wfv, bfv, hv);
    k_pre<<<N_BONDS/128, 256, 0, stream>>>(he, WeP, ye0p, 1);   // h_e0 @ We[128:256]
    k_pre<<<N_ATOMS/128, 256, 0, stream>>>(hv, WvP, yv0p, 1);   // h_v0 @ Wv[128:256]
    hipMemsetAsync(node_sum, 0, (size_t)N_MOLS * DD * 4, stream);
    k_molsum_s<<<N_MOLS*2, 256, 0, stream>>>(hv, amol_ptr, node_sum, 2);
    k_mol_init<<<(N_MOLS*DD)/256, 256, 0, stream>>>(node_sum, Wfu, bfu, hu0);

    const float* hu_in = hu0; float* hu_out = huA;

    for (int r = 0; r < REPEAT; r++) {
        k_yrow<<<(N_MOLS*DD)/256, 256, 0, stream>>>(hu_in, We, be, yue, 512);
        k_yrow<<<(N_MOLS*DD)/256, 256, 0, stream>>>(hu_in, Wv, bv, yuv, 384);
        hipMemsetAsync(ebar, 0, (size_t)N_MOLS * DD * 4, stream);
        hipMemsetAsync(vbar, 0, (size_t)N_MOLS * DD * 4, stream);

        k_phi_e2<<<N_BONDS/128, 256, 0, stream>>>(he, hv, WeP, ye0p, yue,
                                                  bsrc, bdst, bmol);
        k_ebar<<<N_ATOMS/16, 256, 0, stream>>>(he, rowptr, adj, ebar_i);
        k_molsum_s<<<N_MOLS*4, 256, 0, stream>>>(he, bmol_ptr, ebar, 4);
        k_phi_v<<<N_ATOMS/128, 256, 0, stream>>>(hv, ebar_i, WvP, yv0p, yuv, amol);
        k_molsum_s<<<N_MOLS*2, 256, 0, stream>>>(hv, amol_ptr, vbar, 2);
        k_phi_u<<<(N_MOLS*DD)/256, 256, 0, stream>>>(hu_in, hu0, ebar, vbar, Wu, bu,
                                                     hu_out, (float*)d_out);

        hu_in = hu_out; hu_out = (hu_out == huA) ? huB : huA;
    }
}